// Round 4
// baseline (246.357 us; speedup 1.0000x reference)
//
#include <hip/hip_runtime.h>
#include <hip/hip_bf16.h>

#define NB 128
#define NT 1024
#define ND 512
#define NDA 576   // 512 (memory) + 64 (im2col window, 62 used + 2 zero pad)
#define NQ 1024
#define NA 128
#define NF 32
#define NK 31
#define CT 32
#define NCHUNK (NT / CT)   // 32
#define ROWB 1152          // bytes per LDS row (576 bf16)

typedef __attribute__((ext_vector_type(8))) short short8;
typedef __attribute__((ext_vector_type(4))) float f32x4;
typedef __attribute__((ext_vector_type(16))) float f32x16;
typedef __attribute__((ext_vector_type(4))) unsigned int u32x4;

__device__ __forceinline__ unsigned short f2bf(float f) {
  unsigned int u = __float_as_uint(f);
  u += 0x7fffu + ((u >> 16) & 1u);   // RNE; inputs are finite
  return (unsigned short)(u >> 16);
}
__device__ __forceinline__ unsigned int cvt_pk_bf16(float lo, float hi) {
  unsigned int r;
  asm("v_cvt_pk_bf16_f32 %0, %1, %2" : "=v"(r) : "v"(lo), "v"(hi));
  return r;
}
__device__ __forceinline__ float bf2f(unsigned short u) {
  return __uint_as_float((unsigned int)u << 16);
}
__device__ __forceinline__ float fast_tanh(float x) {
  const float e = __expf(2.f * x);
  return 1.f - 2.f / (e + 1.f);   // saturates cleanly for |x| large
}
// wt2 packed layout: per (col-tile ct, k-frag kf) a 1KB block of 64 lanes x 16B
// element (a, k): ct=a>>5, al=a&31, kf=k>>4, kr=k&15 ->
//   idx = (ct*36+kf)*512 + (al + ((kr>>3)<<5))*8 + (kr&7)
__device__ __forceinline__ int wt2_off(int a, int k) {
  const int ct = a >> 5, al = a & 31, kf = k >> 4, kr = k & 15;
  return (ct * 36 + kf) * 512 + (al + ((kr >> 3) << 5)) * 8 + (kr & 7);
}

// ---------------------------------------------------------------------------
// Prep: pq partials (0..511), Wm^T -> wt2 bf16 (512..575), W2=ck@Wloc (576..583)
// ---------------------------------------------------------------------------
__global__ __launch_bounds__(256) void lsa_prep(
    const float* __restrict__ query, const float* __restrict__ wq,
    const float* __restrict__ wm, const float* __restrict__ ck,
    const float* __restrict__ wloc,
    float* __restrict__ pq_part, unsigned short* __restrict__ wt2)
{
  const int bid = blockIdx.x;
  const int tid = threadIdx.x;
  if (bid < 512) {
    __shared__ float qs[256];
    __shared__ float red[256];
    const int b = bid >> 2;
    const int qg = bid & 3;
    qs[tid] = query[(size_t)b * NQ + qg * 256 + tid];
    __syncthreads();
    const int a = tid & 127;
    const int h = tid >> 7;
    const float* wqp = wq + (size_t)(qg * 256 + h * 128) * NA + a;
    float acc = 0.f;
#pragma unroll 8
    for (int qi = 0; qi < 128; ++qi)
      acc += qs[h * 128 + qi] * wqp[(size_t)qi * NA];
    red[tid] = acc;
    __syncthreads();
    if (h == 0) pq_part[((size_t)b * 4 + qg) * NA + a] = red[a] + red[128 + a];
  } else if (bid < 576) {
    const int blk = bid - 512;   // 0..63
    for (int i = blk * 1024 + tid; i < blk * 1024 + 1024; i += 256) {
      const int dd = i >> 7, aa = i & 127;
      wt2[wt2_off(aa, dd)] = f2bf(wm[(size_t)dd * NA + aa]);
    }
  } else {
    // W2[w][a] = sum_f ck[k][ch][f]*wloc[f][a], w=2k+ch; w=62,63 -> 0
    __shared__ float wl_s[NF * NA];
    __shared__ float ck_s[NK * 2 * NF];
    const int blk = bid - 576;   // 0..7
    for (int i = tid; i < NF * NA; i += 256) wl_s[i] = wloc[i];
    for (int i = tid; i < NK * 2 * NF; i += 256) ck_s[i] = ck[i];
    __syncthreads();
    const int a = tid & 127;
    const int h = tid >> 7;
#pragma unroll
    for (int wi = 0; wi < 4; ++wi) {
      const int w = blk * 8 + h * 4 + wi;
      float acc = 0.f;
      if (w < 62) {
        const int k = w >> 1, ch = w & 1;
#pragma unroll
        for (int f = 0; f < NF; ++f)
          acc += ck_s[k * 64 + ch * 32 + f] * wl_s[f * NA + a];
      }
      wt2[wt2_off(a, 512 + w)] = f2bf(acc);
    }
  }
}

// ---------------------------------------------------------------------------
// Main: persistent per-(b, quarter) block; chunk loop ci = q, q+4, ...
// waves 0-3: 32x32x16 MFMA GEMM + softmax + context; waves 4-7: reg-staging
// pipeline (load chunk j+2, write chunk j+1) into double-buffered LDS.
// ---------------------------------------------------------------------------
__global__ __launch_bounds__(512, 4) void lsa_main(
    const float* __restrict__ memory, const int* __restrict__ msl,
    const float* __restrict__ prev, const float* __restrict__ cum,
    const float* __restrict__ pq_part, const float* __restrict__ v_g,
    const unsigned short* __restrict__ wt2,
    float* __restrict__ score_g, float* __restrict__ pm_g,
    float* __restrict__ pl_g, float* __restrict__ pctx_g)
{
  const int bid = blockIdx.x;
  const int b = bid >> 2;
  const int q = bid & 3;
  const int len = msl[b];
  const int ncv = (len + 31) >> 5;          // valid chunks in this batch
  const int nk = (ncv - q + 3) >> 2;        // chunks this block handles (>=4)
  const int tid = threadIdx.x;
  const int wid = tid >> 6;
  const int lane = tid & 63;

  __shared__ __align__(16) unsigned short sv[2][CT * NDA];  // 2 x 36 KB
  __shared__ float score2[4][CT];
  __shared__ float pq_s[NA];
  __shared__ float v_s[NA];

  float st[8][8];   // staging registers (waves 4-7): one chunk in flight

  // ---------------- prologue ----------------
  if (wid < 4) {
    if (tid < NA) {
      const float* pp = pq_part + (size_t)b * 4 * NA + tid;
      pq_s[tid] = pp[0] + pp[NA] + pp[2 * NA] + pp[3 * NA];
      v_s[tid] = v_g[tid];
    }
  } else {
    const int sw = wid - 4;
    const int rr = sw * 8 + (lane & 7);          // row 0..31
    const int s8 = (lane >> 3) ^ (lane & 7);     // permuted 16B slot
    const int m = ((rr & 7) << 4) ^ (((rr >> 3) & 3) << 7);
    // chunk 0: load -> cvt -> write buf0
    {
      const float* src = memory + ((size_t)b * NT + q * CT + rr) * ND + s8 * 8;
      char* dstrow = (char*)sv[0] + rr * ROWB;
#pragma unroll
      for (int it = 0; it < 8; ++it) {
        const f32x4 x0 = *(const f32x4*)(src + it * 64);
        const f32x4 x1 = *(const f32x4*)(src + it * 64 + 4);
        u32x4 pk;
        pk[0] = cvt_pk_bf16(x0[0], x0[1]);
        pk[1] = cvt_pk_bf16(x0[2], x0[3]);
        pk[2] = cvt_pk_bf16(x1[0], x1[1]);
        pk[3] = cvt_pk_bf16(x1[2], x1[3]);
        *(u32x4*)(dstrow + ((s8 * 16 + it * 128) ^ m)) = pk;
      }
    }
    // im2col chunk 0
    {
      const int idx = tid - 256;
      const int r2 = idx >> 3, x8 = idx & 7;
      const int t0c = q * CT;
      float xv[8];
#pragma unroll
      for (int i = 0; i < 8; ++i) {
        const int w = x8 * 8 + i;
        float val = 0.f;
        if (w < 62) {
          const int t3 = t0c - 15 + (w >> 1) + r2;
          if (t3 >= 0 && t3 < NT)
            val = (w & 1) ? cum[(size_t)b * NT + t3] : prev[(size_t)b * NT + t3];
        }
        xv[i] = val;
      }
      u32x4 pk;
      pk[0] = cvt_pk_bf16(xv[0], xv[1]);
      pk[1] = cvt_pk_bf16(xv[2], xv[3]);
      pk[2] = cvt_pk_bf16(xv[4], xv[5]);
      pk[3] = cvt_pk_bf16(xv[6], xv[7]);
      *(u32x4*)((char*)sv[0] + r2 * ROWB + ((1024 + x8 * 16) ^ ((r2 & 7) << 4))) = pk;
    }
    // issue loads for chunk 1
    if (nk > 1) {
      const float* src = memory + ((size_t)b * NT + (q + 4) * CT + rr) * ND + s8 * 8;
#pragma unroll
      for (int it = 0; it < 8; ++it) {
        const f32x4 x0 = *(const f32x4*)(src + it * 64);
        const f32x4 x1 = *(const f32x4*)(src + it * 64 + 4);
#pragma unroll
        for (int u2 = 0; u2 < 4; ++u2) { st[it][u2] = x0[u2]; st[it][4 + u2] = x1[u2]; }
      }
    }
  }
  __syncthreads();

  // ---------------- chunk loop ----------------
  const int r31 = lane & 31;
  const int Mlo = ((r31 & 7) << 4) ^ (((r31 >> 3) & 3) << 7);
  const int Mhi = ((r31 & 7) << 4);
  const int kh = (lane >> 5) * 16;

  for (int j = 0; j < nk; ++j) {
    const int ci = q + 4 * j;
    const int cid = b * NCHUNK + ci;
    const int nvalid = min(CT, len - ci * CT);
    const char* bufp = (const char*)sv[j & 1];
    float esc = 0.f;   // per-lane softmax weight (waves 0-3)

    if (wid < 4) {
      // ---- GEMM: 32(t) x 32(a per wave) x 576(k), 32x32x16 MFMA ----
      const unsigned short* bb = wt2 + (size_t)(wid * 36) * 512 + lane * 8;
      const char* arow = bufp + r31 * ROWB;
      f32x16 acc = {0.f,0.f,0.f,0.f,0.f,0.f,0.f,0.f,0.f,0.f,0.f,0.f,0.f,0.f,0.f,0.f};
#pragma unroll
      for (int kf = 0; kf < 36; ++kf) {
        const short8 bfr = *(const short8*)(bb + kf * 512);
        const int x = kf * 32 + kh;
        const short8 afr = *(const short8*)(arow + (x ^ (kf < 32 ? Mlo : Mhi)));
        acc = __builtin_amdgcn_mfma_f32_32x32x16_bf16(afr, bfr, acc, 0, 0, 0);
      }
      // ---- epilogue: tanh(acc+pq)*v, row-sum over this wave's 32 cols ----
      const float pqc = pq_s[wid * 32 + r31];
      const float vc = v_s[wid * 32 + r31];
#pragma unroll
      for (int rg = 0; rg < 16; ++rg) {
        float e = fast_tanh(acc[rg] + pqc) * vc;
        e += __shfl_xor(e, 1);  e += __shfl_xor(e, 2);  e += __shfl_xor(e, 4);
        e += __shfl_xor(e, 8);  e += __shfl_xor(e, 16);
        if (r31 == 0)
          score2[wid][(rg & 3) + 8 * (rg >> 2) + 4 * (lane >> 5)] = e;
      }
    }
    __syncthreads();   // score2 ready; buf(j+1) staged (written last iter)

    if (wid < 4) {
      // ---- redundant per-wave softmax (no extra barrier) ----
      const int t = r31;
      const float s = score2[0][t] + score2[1][t] + score2[2][t] + score2[3][t];
      if (wid == 0 && lane < 32) score_g[(size_t)b * NT + ci * CT + t] = s;
      float sm = (t < nvalid) ? s : -3.4e38f;
      sm = fmaxf(sm, __shfl_xor(sm, 1));  sm = fmaxf(sm, __shfl_xor(sm, 2));
      sm = fmaxf(sm, __shfl_xor(sm, 4));  sm = fmaxf(sm, __shfl_xor(sm, 8));
      sm = fmaxf(sm, __shfl_xor(sm, 16));
      esc = (t < nvalid) ? __expf(s - sm) : 0.f;
      float l = esc;
      l += __shfl_xor(l, 1);  l += __shfl_xor(l, 2);  l += __shfl_xor(l, 4);
      l += __shfl_xor(l, 8);  l += __shfl_xor(l, 16);
      if (wid == 0 && lane == 0) { pm_g[cid] = sm; pl_g[cid] = l; }
      // ---- context from LDS copy; waves 0-3 cover 512 d's ----
      const int gi = lane >> 2;
      const int g = wid * 16 + gi;        // d-group, d0 = 8g
      const int sub = lane & 3;
      float a8[8];
#pragma unroll
      for (int i = 0; i < 8; ++i) a8[i] = 0.f;
#pragma unroll
      for (int tp = 0; tp < 8; ++tp) {
        const int t2 = tp * 4 + sub;
        const float ee = __shfl(esc, t2);
        const int m2 = ((t2 & 7) << 4) ^ (((t2 >> 3) & 3) << 7);
        const short8 u = *(const short8*)(bufp + t2 * ROWB + ((g * 16) ^ m2));
#pragma unroll
        for (int i = 0; i < 8; ++i) a8[i] += ee * bf2f((unsigned short)u[i]);
      }
#pragma unroll
      for (int i = 0; i < 8; ++i) {
        a8[i] += __shfl_xor(a8[i], 1);
        a8[i] += __shfl_xor(a8[i], 2);
      }
      if (sub == 0) {
        float* dst = pctx_g + (size_t)cid * ND + g * 8;
        const f32x4 lo = {a8[0], a8[1], a8[2], a8[3]};
        const f32x4 hi = {a8[4], a8[5], a8[6], a8[7]};
        *(f32x4*)dst = lo;
        *(f32x4*)(dst + 4) = hi;
      }
    } else {
      // ---- staging waves ----
      const int sw = wid - 4;
      const int rr = sw * 8 + (lane & 7);
      const int s8 = (lane >> 3) ^ (lane & 7);
      const int m = ((rr & 7) << 4) ^ (((rr >> 3) & 3) << 7);
      if (j + 1 < nk) {
        // write chunk j+1 (loaded one iter ago) into buf (j+1)&1
        char* dstrow = (char*)sv[(j + 1) & 1] + rr * ROWB;
#pragma unroll
        for (int it = 0; it < 8; ++it) {
          u32x4 pk;
          pk[0] = cvt_pk_bf16(st[it][0], st[it][1]);
          pk[1] = cvt_pk_bf16(st[it][2], st[it][3]);
          pk[2] = cvt_pk_bf16(st[it][4], st[it][5]);
          pk[3] = cvt_pk_bf16(st[it][6], st[it][7]);
          *(u32x4*)(dstrow + ((s8 * 16 + it * 128) ^ m)) = pk;
        }
        // im2col chunk j+1
        const int idx = tid - 256;
        const int r2 = idx >> 3, x8 = idx & 7;
        const int t0n = (q + 4 * (j + 1)) * CT;
        float xv[8];
#pragma unroll
        for (int i = 0; i < 8; ++i) {
          const int w = x8 * 8 + i;
          float val = 0.f;
          if (w < 62) {
            const int t3 = t0n - 15 + (w >> 1) + r2;
            if (t3 >= 0 && t3 < NT)
              val = (w & 1) ? cum[(size_t)b * NT + t3] : prev[(size_t)b * NT + t3];
          }
          xv[i] = val;
        }
        u32x4 pk;
        pk[0] = cvt_pk_bf16(xv[0], xv[1]);
        pk[1] = cvt_pk_bf16(xv[2], xv[3]);
        pk[2] = cvt_pk_bf16(xv[4], xv[5]);
        pk[3] = cvt_pk_bf16(xv[6], xv[7]);
        *(u32x4*)((char*)sv[(j + 1) & 1] + r2 * ROWB +
                  ((1024 + x8 * 16) ^ ((r2 & 7) << 4))) = pk;
      }
      if (j + 2 < nk) {
        // issue loads for chunk j+2 into st
        const float* src =
            memory + ((size_t)b * NT + (q + 4 * (j + 2)) * CT + rr) * ND + s8 * 8;
#pragma unroll
        for (int it = 0; it < 8; ++it) {
          const f32x4 x0 = *(const f32x4*)(src + it * 64);
          const f32x4 x1 = *(const f32x4*)(src + it * 64 + 4);
#pragma unroll
          for (int u2 = 0; u2 < 4; ++u2) { st[it][u2] = x0[u2]; st[it][4 + u2] = x1[u2]; }
        }
      }
    }
    __syncthreads();   // buf(j+1) complete; context j done (buf j&1 free)
  }
}

// ---------------------------------------------------------------------------
// Combine: merge chunk partials; write context, attn, new_cum. Grid NB*2.
// ---------------------------------------------------------------------------
__global__ __launch_bounds__(256) void lsa_comb(
    const int* __restrict__ msl, const float* __restrict__ score_g,
    const float* __restrict__ cum, const float* __restrict__ pm_g,
    const float* __restrict__ pl_g, const float* __restrict__ pctx_g,
    float* __restrict__ out)
{
  const int bid = blockIdx.x;
  const int b = bid >> 1;
  const int hf = bid & 1;
  const int tid = threadIdx.x;
  const int len = msl[b];
  const int nck = (len + CT - 1) / CT;
  __shared__ float coef[NCHUNK];
  __shared__ float MLsh[2];
  if (tid < 64) {
    const int i = tid;
    const float m = (i < nck) ? pm_g[b * NCHUNK + i] : -3.4e38f;
    const float l = (i < nck) ? pl_g[b * NCHUNK + i] : 0.f;
    float M = m;
#pragma unroll
    for (int off = 1; off < 64; off <<= 1) M = fmaxf(M, __shfl_xor(M, off));
    const float c = __expf(m - M);
    float L = l * c;
#pragma unroll
    for (int off = 1; off < 64; off <<= 1) L += __shfl_xor(L, off);
    if (i < NCHUNK) coef[i] = c;
    if (i == 0) { MLsh[0] = M; MLsh[1] = L; }
  }
  __syncthreads();
  const float M = MLsh[0];
  const float Linv = 1.f / MLsh[1];
  {
    const int d = hf * 256 + tid;
    float acc = 0.f;
    for (int i = 0; i < nck; ++i)
      acc += pctx_g[((size_t)b * NCHUNK + i) * ND + d] * coef[i];
    out[(size_t)b * ND + d] = acc * Linv;
  }
  float* attn_o = out + (size_t)NB * ND;
  float* cum_o = attn_o + (size_t)NB * NT;
#pragma unroll
  for (int it = 0; it < 2; ++it) {
    const int t = hf * 512 + it * 256 + tid;
    float w = 0.f;
    if (t < len) w = __expf(score_g[(size_t)b * NT + t] - M) * Linv;
    attn_o[(size_t)b * NT + t] = w;
    cum_o[(size_t)b * NT + t] = w + cum[(size_t)b * NT + t];
  }
}

extern "C" void kernel_launch(void* const* d_in, const int* in_sizes, int n_in,
                              void* d_out, int out_size, void* d_ws, size_t ws_size,
                              hipStream_t stream) {
  const float* query  = (const float*)d_in[0];
  const float* prev   = (const float*)d_in[1];
  const float* cum    = (const float*)d_in[2];
  const float* memory = (const float*)d_in[3];
  const int*   msl    = (const int*)d_in[4];
  const float* wq     = (const float*)d_in[5];
  const float* wm     = (const float*)d_in[6];
  const float* ck     = (const float*)d_in[7];
  const float* wloc   = (const float*)d_in[8];
  const float* vv     = (const float*)d_in[9];
  float* out = (float*)d_out;

  // workspace layout (floats), ~9.4 MB
  float* ws = (float*)d_ws;
  float* score_g = ws;                        // 131072
  float* pm_g    = ws + 131072;               // 4096
  float* pl_g    = ws + 135168;               // 4096
  float* pctx_g  = ws + 139264;               // 2097152
  float* pq_part = ws + 2236416;              // 65536
  unsigned short* wt2 = (unsigned short*)(ws + 2301952);  // 4*36*512 bf16

  lsa_prep<<<584, 256, 0, stream>>>(query, wq, wm, ck, wloc, pq_part, wt2);
  lsa_main<<<NB * 4, 512, 0, stream>>>(memory, msl, prev, cum, pq_part, vv,
                                       wt2, score_g, pm_g, pl_g, pctx_g);
  lsa_comb<<<NB * 2, 256, 0, stream>>>(msl, score_g, cum, pm_g, pl_g, pctx_g, out);
}

// Round 5
// 103.422 us; speedup vs baseline: 2.3821x; 2.3821x over previous
//
#include <hip/hip_runtime.h>
#include <hip/hip_bf16.h>

#define NB 128
#define NT 1024
#define ND 512
#define NDA 576   // 512 (memory) + 64 (im2col window, 62 used + 2 zero pad)
#define NQ 1024
#define NA 128
#define NF 32
#define NK 31
#define CT 32
#define NCHUNK (NT / CT)   // 32

typedef __attribute__((ext_vector_type(8))) short short8;
typedef __attribute__((ext_vector_type(4))) float f32x4;
typedef __attribute__((ext_vector_type(4))) unsigned int u32x4;
typedef __attribute__((ext_vector_type(2))) unsigned int u32x2;

__device__ __forceinline__ unsigned short f2bf(float f) {
  unsigned int u = __float_as_uint(f);
  u += 0x7fffu + ((u >> 16) & 1u);   // RNE; inputs are finite
  return (unsigned short)(u >> 16);
}
__device__ __forceinline__ unsigned int cvt_pk_bf16(float lo, float hi) {
  unsigned int r;
  asm("v_cvt_pk_bf16_f32 %0, %1, %2" : "=v"(r) : "v"(lo), "v"(hi));
  return r;
}
__device__ __forceinline__ float bf2f(unsigned short u) {
  return __uint_as_float((unsigned int)u << 16);
}
// 2 transcendental ops; exact saturation at both tails, no branches
__device__ __forceinline__ float fast_tanh(float x) {
  const float e = __expf(2.f * x);
  return 1.f - 2.f / (e + 1.f);
}

// ---------------------------------------------------------------------------
// Prep: pq partials (blocks 0..511), Wm^T -> bf16 (512..575), W2 = ck@Wloc
// (576..583). All well-parallelized; no serial latency chains.
// ---------------------------------------------------------------------------
__global__ __launch_bounds__(256) void lsa_prep(
    const float* __restrict__ query, const float* __restrict__ wq,
    const float* __restrict__ wm, const float* __restrict__ ck,
    const float* __restrict__ wloc,
    float* __restrict__ pq_part, unsigned short* __restrict__ wt_g)
{
  const int bid = blockIdx.x;
  const int tid = threadIdx.x;
  if (bid < 512) {
    __shared__ float qs[256];
    __shared__ float red[256];
    const int b = bid >> 2;
    const int qg = bid & 3;
    qs[tid] = query[(size_t)b * NQ + qg * 256 + tid];
    __syncthreads();
    const int a = tid & 127;
    const int h = tid >> 7;
    const float* wqp = wq + (size_t)(qg * 256 + h * 128) * NA + a;
    float acc = 0.f;
#pragma unroll 8
    for (int qi = 0; qi < 128; ++qi)
      acc += qs[h * 128 + qi] * wqp[(size_t)qi * NA];
    red[tid] = acc;
    __syncthreads();
    if (h == 0) pq_part[((size_t)b * 4 + qg) * NA + a] = red[a] + red[128 + a];
  } else if (bid < 576) {
    // Wt[a][d] = bf16(Wm[d][a]), row stride NDA
    const int blk = bid - 512;   // 0..63, 8 d-rows each
    for (int i = blk * 1024 + tid; i < blk * 1024 + 1024; i += 256) {
      const int dd = i >> 7, aa = i & 127;
      wt_g[(size_t)aa * NDA + dd] = f2bf(wm[(size_t)dd * NA + aa]);
    }
  } else {
    // W2[w][a] = sum_f ck[k][ch][f]*wloc[f][a], w = 2k+ch; rows 62,63 = 0.
    __shared__ float wl_s[NF * NA];
    __shared__ float ck_s[NK * 2 * NF];
    const int blk = bid - 576;         // 0..7, 8 w's each
    for (int i = tid; i < NF * NA; i += 256) wl_s[i] = wloc[i];
    for (int i = tid; i < NK * 2 * NF; i += 256) ck_s[i] = ck[i];
    __syncthreads();
    const int a = tid & 127;
    const int h = tid >> 7;
#pragma unroll
    for (int wi = 0; wi < 4; ++wi) {
      const int w = blk * 8 + h * 4 + wi;
      float acc = 0.f;
      if (w < 62) {
        const int k = w >> 1, ch = w & 1;
#pragma unroll
        for (int f = 0; f < NF; ++f)
          acc += ck_s[k * 64 + ch * 32 + f] * wl_s[f * NA + a];
      }
      wt_g[(size_t)a * NDA + 512 + w] = f2bf(acc);
    }
  }
}

// ---------------------------------------------------------------------------
// Main (R3 structure + fast_tanh + all-wave softmax, 2 barriers):
// per (b, 32-row chunk): augmented GEMM [values|window]@[Wt;W2] -> fast_tanh
// -> redundant per-wave softmax -> partial context from the same LDS copy.
// ---------------------------------------------------------------------------
__global__ __launch_bounds__(512, 6) void lsa_main(
    const float* __restrict__ memory, const int* __restrict__ msl,
    const float* __restrict__ prev, const float* __restrict__ cum,
    const float* __restrict__ pq_part, const float* __restrict__ v_g,
    const unsigned short* __restrict__ wt_g,
    float* __restrict__ score_g, float* __restrict__ pm_g,
    float* __restrict__ pl_g, float* __restrict__ pctx_g)
{
  const int bid = blockIdx.x;
  const int b = bid >> 5;
  const int ci = bid & 31;
  const int t0 = ci * CT;
  const int len = msl[b];
  if (t0 >= len) return;                 // fully-masked chunk: combine skips it
  const int nvalid = min(CT, len - t0);
  const int tid = threadIdx.x;

  __shared__ __align__(16) unsigned short sv[CT * NDA];  // 36 KB, swizzled bf16
  __shared__ float pwin_s[62];
  __shared__ float cwin_s[62];
  __shared__ float pq_s[NA];
  __shared__ float v_s[NA];
  __shared__ float score2[8][CT];

  // ---- stage values -> bf16 LDS (first 1024B of each 1152B row), swizzled --
  {
    const int r = tid >> 4;        // 0..31
    const int j = tid & 15;
    const float* src = memory + ((size_t)b * NT + (t0 + r)) * ND;
    char* svb = (char*)sv + r * 1152;
    const int sw = (r & 7) << 4;
#pragma unroll
    for (int it = 0; it < 4; ++it) {
      const int e0 = j * 8 + it * 128;
      f32x4 x0 = *(const f32x4*)(src + e0);
      f32x4 x1 = *(const f32x4*)(src + e0 + 4);
      u32x4 pk;
      pk[0] = cvt_pk_bf16(x0[0], x0[1]);
      pk[1] = cvt_pk_bf16(x0[2], x0[3]);
      pk[2] = cvt_pk_bf16(x1[0], x1[1]);
      pk[3] = cvt_pk_bf16(x1[2], x1[3]);
      *(u32x4*)(svb + ((e0 * 2) ^ sw)) = pk;
    }
  }
  // prev/cum windows [t0-15, t0+46] (62 each)
  if (tid < 124) {
    const int j = tid >> 1, chn = tid & 1;
    const int tt = t0 - 15 + j;
    const float val = (tt >= 0 && tt < NT)
        ? (chn ? cum : prev)[(size_t)b * NT + tt] : 0.f;
    (chn ? cwin_s : pwin_s)[j] = val;
  }
  if (tid >= 384) {   // separate wave: pq (sum 4 partials) and v
    const int a = tid - 384;
    v_s[a] = v_g[a];
    const float* pp = pq_part + (size_t)b * 4 * NA + a;
    pq_s[a] = pp[0] + pp[NA] + pp[2 * NA] + pp[3 * NA];
  }
  __syncthreads();

  // ---- build im2col X into cols 512..575 (bytes 1024..1151 of each row) ----
  {
    const int t = tid >> 4;
    const int w0 = (tid & 15) * 4;
    float xv[4];
#pragma unroll
    for (int i = 0; i < 4; ++i) {
      const int w = w0 + i;
      xv[i] = 0.f;
      if (w < 62) xv[i] = (w & 1) ? cwin_s[t + (w >> 1)] : pwin_s[t + (w >> 1)];
    }
    u32x2 pk;
    pk[0] = cvt_pk_bf16(xv[0], xv[1]);
    pk[1] = cvt_pk_bf16(xv[2], xv[3]);
    char* dst = (char*)sv + t * 1152 + ((1024 + w0 * 2) ^ ((t & 7) << 4));
    *(u32x2*)dst = pk;
  }
  // NOTE: no barrier needed before GEMM for the im2col part written by the
  // same warps that read it? -- NOT safe: different lanes read it. Barrier:
  __syncthreads();

  // ---- augmented GEMM: 32(t) x 576(k) x 128(a); 8 waves each own 16 cols ---
  const int wid = tid >> 6;
  const int lane = tid & 63;
  const int lhi = lane >> 4, llo = lane & 15;
  {
    const unsigned short* bp = wt_g + (size_t)(wid * 16 + llo) * NDA + lhi * 8;
    const int sw = (llo & 7) << 4;
    const char* a0b = (const char*)sv + llo * 1152;
    const char* a1b = (const char*)sv + (16 + llo) * 1152;
    f32x4 acc0 = {0.f, 0.f, 0.f, 0.f};
    f32x4 acc1 = {0.f, 0.f, 0.f, 0.f};
#pragma unroll
    for (int kf = 0; kf < 18; ++kf) {
      const short8 bb = *(const short8*)(bp + kf * 32);
      const int bo = (kf * 64 + lhi * 16) ^ sw;
      const short8 a0 = *(const short8*)(a0b + bo);
      const short8 a1 = *(const short8*)(a1b + bo);
      acc0 = __builtin_amdgcn_mfma_f32_16x16x32_bf16(a0, bb, acc0, 0, 0, 0);
      acc1 = __builtin_amdgcn_mfma_f32_16x16x32_bf16(a1, bb, acc1, 0, 0, 0);
    }
    // epilogue: fast_tanh(keys+pq)*v, reduce over this wave's 16 cols
    const int c = wid * 16 + llo;
    const float vc = v_s[c];
    const float pqc = pq_s[c];
#pragma unroll
    for (int mf = 0; mf < 2; ++mf) {
      const f32x4 av = mf ? acc1 : acc0;
#pragma unroll
      for (int rg = 0; rg < 4; ++rg) {
        const int r = mf * 16 + lhi * 4 + rg;
        float e = fast_tanh(av[rg] + pqc) * vc;
#pragma unroll
        for (int off = 1; off < 16; off <<= 1) e += __shfl_xor(e, off);
        if (llo == 0) score2[wid][r] = e;
      }
    }
  }
  __syncthreads();

  // ---- redundant all-wave softmax (no extra barrier, no serial wave) ----
  float esc;   // lane t (t = lane&31) holds chunk-softmax weight for row t
  {
    const int t = lane & 31;
    float s = 0.f;
#pragma unroll
    for (int w = 0; w < 8; ++w) s += score2[w][t];
    if (wid == 0 && lane < CT) score_g[(size_t)b * NT + t0 + t] = s;
    float sm = (t < nvalid) ? s : -3.4e38f;
    sm = fmaxf(sm, __shfl_xor(sm, 1));  sm = fmaxf(sm, __shfl_xor(sm, 2));
    sm = fmaxf(sm, __shfl_xor(sm, 4));  sm = fmaxf(sm, __shfl_xor(sm, 8));
    sm = fmaxf(sm, __shfl_xor(sm, 16));
    esc = (t < nvalid) ? __expf(s - sm) : 0.f;
    float l = esc;
    l += __shfl_xor(l, 1);  l += __shfl_xor(l, 2);  l += __shfl_xor(l, 4);
    l += __shfl_xor(l, 8);  l += __shfl_xor(l, 16);
    if (wid == 0 && lane == 0) { pm_g[bid] = sm; pl_g[bid] = l; }
  }

  // ---- partial context from the SAME LDS copy, vectorized ds_read_b128 ----
  // wave w owns d-groups g = 8w..8w+7 (8 d's each); lanes split t 4-ways.
  {
    const int sub = lane & 7;            // t-part: t = sub, sub+8, +16, +24
    const int gi = lane >> 3;            // 0..7
    const int g = wid * 8 + gi;          // d-group, d0 = 8g
    const char* svb = (const char*)sv;
    float acc[8];
#pragma unroll
    for (int i = 0; i < 8; ++i) acc[i] = 0.f;
#pragma unroll
    for (int tp = 0; tp < 4; ++tp) {
      const int t = tp * 8 + sub;
      const float e = __shfl(esc, t);    // lane t holds esc[t]; 0 if invalid
      const short8 u = *(const short8*)(svb + t * 1152 + 16 * (g ^ sub));
#pragma unroll
      for (int i = 0; i < 8; ++i)
        acc[i] += e * bf2f((unsigned short)u[i]);
    }
#pragma unroll
    for (int off = 1; off < 8; off <<= 1) {
#pragma unroll
      for (int i = 0; i < 8; ++i) acc[i] += __shfl_xor(acc[i], off);
    }
    if (sub == 0) {
      float* dst = pctx_g + (size_t)bid * ND + g * 8;
      f32x4 lo = {acc[0], acc[1], acc[2], acc[3]};
      f32x4 hi = {acc[4], acc[5], acc[6], acc[7]};
      *(f32x4*)dst = lo;
      *(f32x4*)(dst + 4) = hi;
    }
  }
}

// ---------------------------------------------------------------------------
// Combine: merge 32 chunk partials per batch; write context, attn, new_cum.
// ---------------------------------------------------------------------------
__global__ __launch_bounds__(512) void lsa_comb(
    const int* __restrict__ msl, const float* __restrict__ score_g,
    const float* __restrict__ cum, const float* __restrict__ pm_g,
    const float* __restrict__ pl_g, const float* __restrict__ pctx_g,
    float* __restrict__ out)
{
  const int b = blockIdx.x;
  const int tid = threadIdx.x;
  const int len = msl[b];
  const int nck = (len + CT - 1) / CT;
  __shared__ float coef[NCHUNK];
  __shared__ float MLsh[2];
  if (tid < 64) {
    const int i = tid;
    const float m = (i < nck) ? pm_g[b * NCHUNK + i] : -3.4e38f;
    const float l = (i < nck) ? pl_g[b * NCHUNK + i] : 0.f;
    float M = m;
#pragma unroll
    for (int off = 1; off < 64; off <<= 1) M = fmaxf(M, __shfl_xor(M, off));
    const float c = __expf(m - M);   // 0 for invalid chunks
    float L = l * c;
#pragma unroll
    for (int off = 1; off < 64; off <<= 1) L += __shfl_xor(L, off);
    if (i < NCHUNK) coef[i] = c;
    if (i == 0) { MLsh[0] = M; MLsh[1] = L; }
  }
  __syncthreads();
  const float M = MLsh[0];
  const float Linv = 1.f / MLsh[1];
  {
    const int d = tid;   // 512 threads == D
    float acc = 0.f;
    for (int i = 0; i < nck; ++i)
      acc += pctx_g[((size_t)b * NCHUNK + i) * ND + d] * coef[i];
    out[(size_t)b * ND + d] = acc * Linv;
  }
  float* attn_o = out + (size_t)NB * ND;
  float* cum_o = attn_o + (size_t)NB * NT;
#pragma unroll
  for (int it = 0; it < 2; ++it) {
    const int t = it * 512 + tid;
    float w = 0.f;
    if (t < len) w = __expf(score_g[(size_t)b * NT + t] - M) * Linv;
    attn_o[(size_t)b * NT + t] = w;
    cum_o[(size_t)b * NT + t] = w + cum[(size_t)b * NT + t];
  }
}

extern "C" void kernel_launch(void* const* d_in, const int* in_sizes, int n_in,
                              void* d_out, int out_size, void* d_ws, size_t ws_size,
                              hipStream_t stream) {
  const float* query  = (const float*)d_in[0];
  const float* prev   = (const float*)d_in[1];
  const float* cum    = (const float*)d_in[2];
  const float* memory = (const float*)d_in[3];
  const int*   msl    = (const int*)d_in[4];
  const float* wq     = (const float*)d_in[5];
  const float* wm     = (const float*)d_in[6];
  const float* ck     = (const float*)d_in[7];
  const float* wloc   = (const float*)d_in[8];
  const float* vv     = (const float*)d_in[9];
  float* out = (float*)d_out;

  // workspace layout (floats), ~9.4 MB total
  float* ws = (float*)d_ws;
  float* score_g = ws;                        // 131072
  float* pm_g    = ws + 131072;               // 4096
  float* pl_g    = ws + 135168;               // 4096
  float* pctx_g  = ws + 139264;               // 2097152
  float* pq_part = ws + 2236416;              // 65536
  unsigned short* wt_g = (unsigned short*)(ws + 2301952);  // 128*576 bf16

  lsa_prep<<<584, 256, 0, stream>>>(query, wq, wm, ck, wloc, pq_part, wt_g);
  lsa_main<<<NB * NCHUNK, 512, 0, stream>>>(memory, msl, prev, cum, pq_part, vv,
                                            wt_g, score_g, pm_g, pl_g, pctx_g);
  lsa_comb<<<NB, 512, 0, stream>>>(msl, score_g, cum, pm_g, pl_g, pctx_g, out);
}